// Round 6
// baseline (132.470 us; speedup 1.0000x reference)
//
#include <hip/hip_runtime.h>
#include <hip/hip_bf16.h>

// QNet: out[i] = w2 . relu( concat(embed[i], graph_embed[rep[i]]) @ w1^T + b1 ) + b2
// Split: pre = embed @ W1a^T (bf16 MFMA, K=64) + Gb[rep[i]] (fp32, MFMA C-init),
// Gb[b][n] = b1[n] + sum_k graph_embed[b][k] * w1[n][64+k].
//
// Single fused kernel. Per block: rep is sorted, so the block's 1024 nodes span
// ~1-2 graphs; thread h computes s_gb[r][h] for r<min(span+1,4) once at start
// (cold per-lane recompute fallback keeps correctness for span>4). Phases refill
// gbv from LDS -> steady-state phases contain NO compiler-tracked global loads.
// 2 waves/block split the hidden dim; shared 4-slot LDS ring staged via
// global_load_lds from a k-major pre-swizzled GLOBAL source (LDS dest linear),
// raw s_barrier + per-wave counted vmcnt, double-buffered LDS dot exchange.

#define D_LAT 64
#define H_HID 128
#define RING  4
#define TPB   64     // tiles per block
#define GBROWS 4

typedef short bf16x8 __attribute__((ext_vector_type(8)));
typedef float f32x4  __attribute__((ext_vector_type(4)));
typedef __attribute__((address_space(3))) float lds_f;

#define MFMA16 __builtin_amdgcn_mfma_f32_16x16x32_bf16

static __device__ inline short f2s(float f) {
    __bf16 h = (__bf16)f;
    return __builtin_bit_cast(short, h);
}
static __device__ inline bf16x8 pack8(f32x4 a, f32x4 b) {
    bf16x8 r;
    r[0] = f2s(a[0]); r[1] = f2s(a[1]); r[2] = f2s(a[2]); r[3] = f2s(a[3]);
    r[4] = f2s(b[0]); r[5] = f2s(b[1]); r[6] = f2s(b[2]); r[7] = f2s(b[3]);
    return r;
}
static __device__ inline void gll16(const float* g, float* l) {
    __builtin_amdgcn_global_load_lds((const __attribute__((address_space(1))) void*)g,
                                     (__attribute__((address_space(3))) void*)l, 16, 0, 0);
}
static __device__ inline void gll4(const int* g, int* l) {
    __builtin_amdgcn_global_load_lds((const __attribute__((address_space(1))) void*)g,
                                     (__attribute__((address_space(3))) void*)l, 4, 0, 0);
}

__global__ __launch_bounds__(128, 4) void qnet_main(
        const float* __restrict__ embed, const int* __restrict__ rep,
        const float* __restrict__ w1, const float* __restrict__ w2,
        const float* __restrict__ b1p, const float* __restrict__ b2,
        const float* __restrict__ ge, float* __restrict__ out) {
    __shared__ float s_emb[RING * 1024];   // 4KB per slot, k-major 16B-unit layout
    __shared__ int   s_rep[RING * 64];
    __shared__ float s_exch[2 * 16];
    __shared__ float s_gb[GBROWS * H_HID]; // 2KB: per-block Gb cache

    const int lane = threadIdx.x & 63;
    const int l15  = lane & 15;
    const int g    = lane >> 4;
    const int w    = threadIdx.x >> 6;        // wave role: 0 / 1 (hidden half)
    const int t0   = blockIdx.x * TPB;

    // ---- per-block Gb rows into LDS (rep sorted -> small span) ----
    const int bmin = rep[t0 * 16];
    const int bmax = rep[(t0 + TPB) * 16 - 1];
    {
        const int span = bmax - bmin;
        const int rows = span < GBROWS ? span + 1 : GBROWS;
        const int h = threadIdx.x;            // 0..127
        const float* wb = w1 + h * (2 * D_LAT) + D_LAT;
        for (int r = 0; r < rows; ++r) {
            const float* ger = ge + (size_t)(bmin + r) * D_LAT;
            float acc = b1p[h];
            #pragma unroll
            for (int kc = 0; kc < 16; ++kc) {
                f32x4 wv = *(const f32x4*)(wb + kc * 4);
                f32x4 gv = *(const f32x4*)(ger + kc * 4);
                acc += wv[0] * gv[0] + wv[1] * gv[1] + wv[2] * gv[2] + wv[3] * gv[3];
            }
            s_gb[r * H_HID + h] = acc;
        }
    }
    __syncthreads();   // harmless full drain: before any pipeline state exists

    // A fragments: this wave's hidden half. lane holds w1[w*64+nt*16+l15][ks*32+g*8+e]
    bf16x8 wfrag[2][4];
    #pragma unroll
    for (int nt = 0; nt < 4; ++nt) {
        const float* wr = w1 + (w * 64 + nt * 16 + l15) * (2 * D_LAT);
        #pragma unroll
        for (int ks = 0; ks < 2; ++ks) {
            f32x4 lo = *reinterpret_cast<const f32x4*>(wr + ks * 32 + g * 8);
            f32x4 hi = *reinterpret_cast<const f32x4*>(wr + ks * 32 + g * 8 + 4);
            wfrag[ks][nt] = pack8(lo, hi);
        }
    }
    f32x4 w2v[4];
    #pragma unroll
    for (int nt = 0; nt < 4; ++nt)
        w2v[nt] = *reinterpret_cast<const f32x4*>(w2 + w * 64 + nt * 16 + g * 4);
    const float b2v = b2[0];

    const unsigned emb_base  = (unsigned)(size_t)(lds_f*)s_emb;
    const unsigned rep_base  = (unsigned)(size_t)(lds_f*)(float*)(void*)s_rep;
    const unsigned exch_base = (unsigned)(size_t)(lds_f*)s_exch;

    int   cur_b = -2;
    f32x4 gbv[4];
    #pragma unroll
    for (int nt = 0; nt < 4; ++nt) gbv[nt] = f32x4{0.f, 0.f, 0.f, 0.f};
    float p_prev = 0.f;

    // k-major pre-swizzled global source: LDS 16B-unit U = j*64+lane holds
    // global unit (row=lane&15, u=j*4+(lane>>4)); src floats = (lane&15)*64 + j*16 + (lane>>4)*4.
#define STAGE_W0(TT, SLOT) do {                                               \
    const float* s0_ = embed + (size_t)(TT) * 1024 + l15 * 64 + g * 4;        \
    float* d_ = s_emb + (SLOT) * 1024;                                        \
    gll16(s0_,      d_);                                                      \
    gll16(s0_ + 16, d_ + 256);                                                \
    gll4(rep + (size_t)(TT) * 16 + l15, s_rep + (SLOT) * 64);                 \
} while (0)
#define STAGE_W1(TT, SLOT) do {                                               \
    const float* s0_ = embed + (size_t)(TT) * 1024 + l15 * 64 + g * 4;        \
    float* d_ = s_emb + (SLOT) * 1024;                                        \
    gll16(s0_ + 32, d_ + 512);                                                \
    gll16(s0_ + 48, d_ + 768);                                                \
} while (0)

    // shared compute tail: refill gbv (LDS cache / cold recompute), MFMA, dot half
#define COMPUTE(P)                                                            \
    int rb0 = __shfl(brow, 0, 64), rb15 = __shfl(brow, 15, 64);               \
    bool uni = (rb0 == rb15);                                                 \
    if (!(uni && rb0 == cur_b)) {                                             \
        const int idx = brow - bmin;                                          \
        const int ic = idx < GBROWS ? idx : (GBROWS - 1);                     \
        const float* sp_ = (const float*)s_gb + ic * H_HID + w * 64 + g * 4;  \
        gbv[0] = *(const f32x4*)(sp_);                                        \
        gbv[1] = *(const f32x4*)(sp_ + 16);                                   \
        gbv[2] = *(const f32x4*)(sp_ + 32);                                   \
        gbv[3] = *(const f32x4*)(sp_ + 48);                                   \
        if (__builtin_expect(idx >= GBROWS, 0)) {                             \
            const float* ger_ = ge + (size_t)brow * D_LAT;                    \
            _Pragma("unroll")                                                 \
            for (int nt = 0; nt < 4; ++nt) {                                  \
                _Pragma("unroll")                                             \
                for (int r = 0; r < 4; ++r) {                                 \
                    const int h_ = w * 64 + nt * 16 + g * 4 + r;              \
                    float a_ = b1p[h_];                                       \
                    const float* wb_ = w1 + h_ * (2 * D_LAT) + D_LAT;         \
                    _Pragma("unroll 1")                                       \
                    for (int k = 0; k < D_LAT; ++k) a_ += ger_[k] * wb_[k];   \
                    gbv[nt][r] = a_;                                          \
                }                                                             \
            }                                                                 \
        }                                                                     \
        cur_b = uni ? rb0 : -1;                                               \
    }                                                                         \
    bf16x8 a0 = pack8(x0, x1), a1 = pack8(x2, x3);                            \
    float P = 0.f;                                                            \
    _Pragma("unroll")                                                         \
    for (int nt = 0; nt < 4; ++nt) {                                          \
        f32x4 z = gbv[nt];                                                    \
        z = MFMA16(wfrag[0][nt], a0, z, 0, 0, 0);                             \
        z = MFMA16(wfrag[1][nt], a1, z, 0, 0, 0);                             \
        _Pragma("unroll")                                                     \
        for (int r = 0; r < 4; ++r) P += fmaxf(z[r], 0.f) * w2v[nt][r];       \
    }                                                                         \
    P += __shfl_xor(P, 16, 64);                                               \
    P += __shfl_xor(P, 32, 64);

#define PH0(CS, TT, I, WN, DOSTAGE, DOSTORE) do {                             \
    asm volatile("s_waitcnt vmcnt(" #WN ")" ::: "memory");                    \
    __builtin_amdgcn_s_barrier();                                             \
    f32x4 x0, x1, x2, x3; int brow; float xv;                                 \
    {                                                                         \
        unsigned ae = emb_base + (unsigned)(CS) * 4096u + g * 512u + l15 * 16u; \
        unsigned ar = rep_base + (unsigned)(CS) * 256u + l15 * 4u;            \
        unsigned ax = exch_base + (unsigned)(((I) - 1) & 1) * 64u + l15 * 4u; \
        asm volatile(                                                         \
            "ds_read_b128 %0, %6\n\t"                                         \
            "ds_read_b128 %1, %6 offset:256\n\t"                              \
            "ds_read_b128 %2, %6 offset:2048\n\t"                             \
            "ds_read_b128 %3, %6 offset:2304\n\t"                             \
            "ds_read_b32  %4, %7\n\t"                                         \
            "ds_read_b32  %5, %8\n\t"                                         \
            "s_waitcnt lgkmcnt(0)"                                            \
            : "=&v"(x0), "=&v"(x1), "=&v"(x2), "=&v"(x3), "=&v"(brow), "=&v"(xv) \
            : "v"(ae), "v"(ar), "v"(ax) : "memory");                          \
    }                                                                         \
    if (DOSTORE) { if (g == 0) out[((TT) - 1) * 16 + l15] = p_prev + xv + b2v; } \
    if (DOSTAGE) STAGE_W0((TT) + 3, ((CS) + 3) & 3);                          \
    COMPUTE(p)                                                                \
    p_prev = p;                                                               \
} while (0)

#define PH1(CS, TT, I, WN, DOSTAGE) do {                                      \
    asm volatile("s_waitcnt vmcnt(" #WN ") lgkmcnt(0)" ::: "memory");         \
    __builtin_amdgcn_s_barrier();                                             \
    f32x4 x0, x1, x2, x3; int brow;                                           \
    {                                                                         \
        unsigned ae = emb_base + (unsigned)(CS) * 4096u + g * 512u + l15 * 16u; \
        unsigned ar = rep_base + (unsigned)(CS) * 256u + l15 * 4u;            \
        asm volatile(                                                         \
            "ds_read_b128 %0, %5\n\t"                                         \
            "ds_read_b128 %1, %5 offset:256\n\t"                              \
            "ds_read_b128 %2, %5 offset:2048\n\t"                             \
            "ds_read_b128 %3, %5 offset:2304\n\t"                             \
            "ds_read_b32  %4, %6\n\t"                                         \
            "s_waitcnt lgkmcnt(0)"                                            \
            : "=&v"(x0), "=&v"(x1), "=&v"(x2), "=&v"(x3), "=&v"(brow)         \
            : "v"(ae), "v"(ar) : "memory");                                   \
    }                                                                         \
    if (DOSTAGE) STAGE_W1((TT) + 3, ((CS) + 3) & 3);                          \
    COMPUTE(p)                                                                \
    {                                                                         \
        unsigned ax = exch_base + (unsigned)((I) & 1) * 64u + l15 * 4u;       \
        if (g == 0)                                                           \
            asm volatile("ds_write_b32 %0, %1" :: "v"(ax), "v"(p) : "memory"); \
    }                                                                         \
} while (0)

    if (w == 0) {
        STAGE_W0(t0 + 0, 0);
        STAGE_W0(t0 + 1, 1);
        STAGE_W0(t0 + 2, 2);
        PH0(0, t0 + 0, 0, 6, true, false);
        PH0(1, t0 + 1, 1, 6, true, true);
        PH0(2, t0 + 2, 2, 7, true, true);
        for (int i = 3; i <= 60; ++i)
            PH0((i & 3), t0 + i, i, 8, true, true);
        PH0(1, t0 + 61, 61, 8, false, true);
        PH0(2, t0 + 62, 62, 5, false, true);
        PH0(3, t0 + 63, 63, 2, false, true);
        // final combine for tile t0+63
        __builtin_amdgcn_s_barrier();
        float xv;
        unsigned ax = exch_base + (unsigned)(63 & 1) * 64u + l15 * 4u;
        asm volatile("ds_read_b32 %0, %1\n\ts_waitcnt lgkmcnt(0)"
                     : "=v"(xv) : "v"(ax) : "memory");
        if (g == 0) out[(t0 + 63) * 16 + l15] = p_prev + xv + b2v;
    } else {
        STAGE_W1(t0 + 0, 0);
        STAGE_W1(t0 + 1, 1);
        STAGE_W1(t0 + 2, 2);
        PH1(0, t0 + 0, 0, 4, true);
        PH1(1, t0 + 1, 1, 4, true);
        PH1(2, t0 + 2, 2, 4, true);
        for (int i = 3; i <= 60; ++i)
            PH1((i & 3), t0 + i, i, 4, true);
        PH1(1, t0 + 61, 61, 4, false);
        PH1(2, t0 + 62, 62, 2, false);
        PH1(3, t0 + 63, 63, 0, false);
        asm volatile("s_waitcnt lgkmcnt(0)" ::: "memory");
        __builtin_amdgcn_s_barrier();
    }

#undef PH0
#undef PH1
#undef COMPUTE
#undef STAGE_W0
#undef STAGE_W1
}

extern "C" void kernel_launch(void* const* d_in, const int* in_sizes, int n_in,
                              void* d_out, int out_size, void* d_ws, size_t ws_size,
                              hipStream_t stream) {
    const float* embed = (const float*)d_in[0];
    const float* ge    = (const float*)d_in[1];
    const int*   rep   = (const int*)d_in[2];
    const float* w1    = (const float*)d_in[3];
    const float* b1    = (const float*)d_in[4];
    const float* w2    = (const float*)d_in[5];
    const float* b2    = (const float*)d_in[6];
    float* out = (float*)d_out;
    (void)d_ws; (void)ws_size; (void)out_size; (void)n_in;

    const int N = in_sizes[0] / D_LAT;
    const int num_tiles = N / 16;

    // single fused dispatch: 2048 blocks x 128 thr, ~19.6KB LDS -> 8 blocks/CU
    qnet_main<<<num_tiles / TPB, 128, 0, stream>>>(embed, rep, w1, w2, b1, b2, ge, out);
}